// Round 8
// baseline (102.463 us; speedup 1.0000x reference)
//
#include <hip/hip_runtime.h>

typedef _Float16 f16;
typedef _Float16 f16x2 __attribute__((ext_vector_type(2)));
typedef _Float16 f16x8 __attribute__((ext_vector_type(8)));
typedef _Float16 f16x4 __attribute__((ext_vector_type(4)));
typedef float f32x4 __attribute__((ext_vector_type(4)));

#define GAS(p) ((const __attribute__((address_space(1))) void*)(p))
#define LAS(p) ((__attribute__((address_space(3))) void*)(p))

__device__ __forceinline__ f32x4 mfma16(f16x8 a, f16x8 b, f32x4 c) {
  return __builtin_amdgcn_mfma_f32_16x16x32_f16(a, b, c, 0, 0, 0);
}

__device__ __forceinline__ f16x2 cvt2(float a, float b) {
  return __builtin_bit_cast(f16x2, __builtin_amdgcn_cvt_pkrtz(a, b));
}

// Stage one 16B chunk per thread into a swizzled LDS tile.
// LDS slot u of row r holds logical col-slot u^(r&7); linear LDS dest +
// inverse-swizzled global source (both-sides-or-neither rule).
__device__ __forceinline__ void stage_tile(const f16* __restrict__ grow0,
                                           int stride_f16, f16* lds, int t) {
  int r = t >> 3;
  int sw = ((t & 7) ^ (r & 7)) * 8;
  __builtin_amdgcn_global_load_lds(GAS(grow0 + r * stride_f16 + sw),
                                   LAS(lds + t * 8), 16, 0, 0);
}

// ---------------- fused fp32->fp16 converts + RoPE tables ----------------
__global__ void convall(const float* __restrict__ x, const float* __restrict__ wq,
                        const float* __restrict__ wk, const float* __restrict__ wv,
                        f16* __restrict__ xh, f16* __restrict__ wh,
                        float* __restrict__ cosT, float* __restrict__ sinT) {
  int bid = blockIdx.x;
  if (bid >= 3584) {  // RoPE tables [2048][32]
    int idx = (bid - 3584) * 256 + threadIdx.x;
    int n = idx >> 5, jj = idx & 31;
    float inv = powf(10000.0f, -(float)jj * (1.0f / 32.0f));
    float ang = (float)n * inv;
    cosT[idx] = cosf(ang);
    sinT[idx] = sinf(ang);
    return;
  }
  const float* s;
  f16* d;
  int boff;
  if (bid < 2048)      { s = x;  d = xh;            boff = bid; }
  else if (bid < 2560) { s = wq; d = wh;            boff = bid - 2048; }
  else if (bid < 3072) { s = wk; d = wh + 1048576;  boff = bid - 2560; }
  else                 { s = wv; d = wh + 2097152;  boff = bid - 3072; }
  int i = (boff * 256 + threadIdx.x) * 8;
  float4 a = *(const float4*)(s + i);
  float4 b = *(const float4*)(s + i + 4);
  f16x8 o = {(f16)a.x, (f16)a.y, (f16)a.z, (f16)a.w,
             (f16)b.x, (f16)b.y, (f16)b.z, (f16)b.w};
  *(f16x8*)(d + i) = o;
}

// ---------------- fused QKV GEMM + RoPE epilogue ----------------
// X: [4096][1024] f16, W: [3072][1024] f16 (Wq|Wk|Wv stacked)
// Q,K out: [32][2048][64] (RoPE applied, Q pre-scaled by log2e/8)
// Vt out:  [32][64][2048] with PERMUTED key coord n' = 32a+8c+4b+r
// so attn's PV A-fragment is one contiguous b128.
__global__ __launch_bounds__(256, 3) void qkv_gemm(
    const f16* __restrict__ X, const f16* __restrict__ W,
    const float* __restrict__ cosT, const float* __restrict__ sinT,
    f16* __restrict__ Q, f16* __restrict__ K, f16* __restrict__ Vt) {
  __shared__ f16 As[128 * 64];
  __shared__ f16 Bs[128 * 64];
  const int tid = threadIdx.x;
  const int wv = tid >> 6, lane = tid & 63;
  const int m0 = blockIdx.x * 128, n0 = blockIdx.y * 128;
  const int cl = lane & 15, g = lane >> 4;
  const int wr = (wv >> 1) * 64, wc = (wv & 1) * 64;
  const int vx = cl & 7;

  f32x4 acc[4][4] = {};
  const f16* ga = X + (size_t)m0 * 1024;
  const f16* gb = W + (size_t)n0 * 1024;

  for (int kt = 0; kt < 1024; kt += 64) {
    __syncthreads();
#pragma unroll
    for (int rd = 0; rd < 4; ++rd) {
      stage_tile(ga + kt, 1024, As, tid + rd * 256);
      stage_tile(gb + kt, 1024, Bs, tid + rd * 256);
    }
    __syncthreads();  // compiler drains vmcnt before barrier
#pragma unroll
    for (int kk = 0; kk < 2; ++kk) {
      f16x8 a[4], bf[4];
#pragma unroll
      for (int mi = 0; mi < 4; ++mi)
        a[mi] = *(const f16x8*)(As + (wr + mi * 16 + cl) * 64 +
                                (((kk * 4 + g) ^ vx) << 3));
#pragma unroll
      for (int ni = 0; ni < 4; ++ni)
        bf[ni] = *(const f16x8*)(Bs + (wc + ni * 16 + cl) * 64 +
                                 (((kk * 4 + g) ^ vx) << 3));
#pragma unroll
      for (int mi = 0; mi < 4; ++mi)
#pragma unroll
        for (int ni = 0; ni < 4; ++ni)
          acc[mi][ni] = mfma16(a[mi], bf[ni], acc[mi][ni]);
    }
  }

  // epilogue: C/D layout col=lane&15 row=(lane>>4)*4+reg
  const int p = n0 >> 10;  // 0=q 1=k 2=v
  for (int mi = 0; mi < 4; ++mi) {
    int rbase = m0 + wr + mi * 16 + g * 4;
    for (int ni = 0; ni < 4; ++ni) {
      int gc = n0 + wc + ni * 16 + cl;
      int f = gc & 1023;
      int h = f >> 6, d = f & 63;
      if (p < 2) {
        int j = d >> 1;
        f16* dst = (p == 0) ? Q : K;
        // Q pre-scale folds softmax 1/8 and log2(e) (exp2-domain scores)
        float sc = (p == 0) ? 0.18033688011f : 1.0f;
        for (int r = 0; r < 4; ++r) {
          int row = rbase + r;
          int bb = row >> 11, n = row & 2047;
          float co = cosT[n * 32 + j], si = sinT[n * 32 + j];
          float v = acc[mi][ni][r];
          float pr = __shfl_xor(v, 1);
          float o = (d & 1) ? (v * co + pr * si) : (v * co - pr * si);
          dst[((bb * 16 + h) * 2048 + n) * 64 + d] = (f16)(o * sc);
        }
      } else {
        int bb = rbase >> 11, n = rbase & 2047;
        // permuted key coord (4-aligned block): n' = 32a | 8c | 4b
        int np = (n & ~31) | (((n >> 2) & 3) << 3) | (((n >> 4) & 1) << 2);
        f16x4 pk = {(f16)acc[mi][ni][0], (f16)acc[mi][ni][1],
                    (f16)acc[mi][ni][2], (f16)acc[mi][ni][3]};
        *(f16x4*)(Vt + (size_t)((bb * 16 + h) * 64 + d) * 2048 + np) = pk;
      }
    }
  }
}

// ---------------- flash attention fwd v8: 8-phase schedule (T3+T4) --------
// grid 512 x 256 thr; block = 128 q (4 waves x 32 q), KVBLK=64, 2 blocks/CU.
// Per K-tile: 4 sub-phases, each {4 ds_read (this phase's frags) + 1 stage
// instr of tile it+2 -> s_barrier -> lgkmcnt(0) -> setprio(1) -> 8 MFMA ->
// setprio(0) -> s_barrier}. Softmax VALU in Ph3/Ph4 pre-barrier shadow.
// Triple buffer; counted vmcnt(4) once/iter (4 stage instr/wave/tile,
// 2-ahead, in-order retirement => tile it+1 landed). Never drain mid-loop.
__global__ __launch_bounds__(256, 2) void attn(
    const f16* __restrict__ Q, const f16* __restrict__ K,
    const f16* __restrict__ Vt, float* __restrict__ out) {
  __shared__ f16 Ks[3][4096];   // [key][d], XOR-swizzled 16B slots
  __shared__ f16 Vs[3][4096];   // [d][key'], XOR-swizzled 16B slots
  const int tid = threadIdx.x;
  const int w = tid >> 6, lane = tid & 63;
  const int cl = lane & 15, g = lane >> 4;
  const int id = blockIdx.x;
  const int xcd = id & 7, j = id >> 3;  // XCD-grouped: 4 bh per XCD
  const int bh = xcd * 4 + (j >> 4);
  const int b = bh >> 4, h = bh & 15;
  const int qb = (j & 15) * 128 + w * 32;  // wave's 32-q base
  const f16* Qp = Q + (size_t)bh * (2048 * 64);
  const f16* Kp = K + (size_t)bh * (2048 * 64);
  const f16* Vp = Vt + (size_t)bh * (64 * 2048);

  // Q as B-operand: col=q=cl (per half), k=d (pre-scaled by log2e/8)
  f16x8 bq[2][2];
#pragma unroll
  for (int qh = 0; qh < 2; ++qh) {
    bq[qh][0] = *(const f16x8*)(Qp + (qb + qh * 16 + cl) * 64 + g * 8);
    bq[qh][1] = *(const f16x8*)(Qp + (qb + qh * 16 + cl) * 64 + 32 + g * 8);
  }

  f32x4 acc[2][4] = {};   // acc[qh][dblk]: O^T[d=dblk*16+g*4+r][q]
  float lsp[2] = {0.f, 0.f};
  const int vx = cl & 7;
  const f32x4 z4 = {0.f, 0.f, 0.f, 0.f};

#define STG_K(T, B, C) stage_tile(Kp + (size_t)(T) * 4096, 64, Ks[B], tid + (C) * 256)
#define STG_V(T, B, C) stage_tile(Vp + (size_t)(T) * 64, 2048, Vs[B], tid + (C) * 256)

  // prologue: tiles 0,1 — per tile 4 instrs in order K,K,V,V
  STG_K(0, 0, 0); STG_K(0, 0, 1); STG_V(0, 0, 0); STG_V(0, 0, 1);
  STG_K(1, 1, 0); STG_K(1, 1, 1); STG_V(1, 1, 0); STG_V(1, 1, 1);

  int cur = 0;
  union PB { f16x8 v; f16x2 hx[4]; };
  for (int it = 0; it < 32; ++it) {
    const int nb = (cur == 0) ? 2 : cur - 1;  // (cur+2)%3
    const bool st = (it + 2 < 32);
    // tile `it` landed when outstanding <= 4 (in-order retirement)
    if (it >= 30)
      asm volatile("s_waitcnt vmcnt(0)" ::: "memory");
    else
      asm volatile("s_waitcnt vmcnt(4)" ::: "memory");
    __builtin_amdgcn_s_barrier();
    const f16* kb = Ks[cur];
    const f16* vb = Vs[cur];
    f32x4 s[2][4];

    // ---- Phase 1: K frags i=0,1 ; stage K-a(it+2) ; QK^T i=0,1 ----
    {
      const f16* kr0 = kb + (0 * 16 + cl) * 64;
      const f16* kr1 = kb + (1 * 16 + cl) * 64;
      f16x8 p1a0 = *(const f16x8*)(kr0 + ((g ^ vx) << 3));
      f16x8 p1a1 = *(const f16x8*)(kr0 + (((4 + g) ^ vx) << 3));
      f16x8 p1b0 = *(const f16x8*)(kr1 + ((g ^ vx) << 3));
      f16x8 p1b1 = *(const f16x8*)(kr1 + (((4 + g) ^ vx) << 3));
      if (st) STG_K(it + 2, nb, 0);
      __builtin_amdgcn_s_barrier();
      asm volatile("s_waitcnt lgkmcnt(0)" ::: "memory");
      __builtin_amdgcn_sched_barrier(0);
      __builtin_amdgcn_s_setprio(1);
      s[0][0] = mfma16(p1a1, bq[0][1], mfma16(p1a0, bq[0][0], z4));
      s[1][0] = mfma16(p1a1, bq[1][1], mfma16(p1a0, bq[1][0], z4));
      s[0][1] = mfma16(p1b1, bq[0][1], mfma16(p1b0, bq[0][0], z4));
      s[1][1] = mfma16(p1b1, bq[1][1], mfma16(p1b0, bq[1][0], z4));
      __builtin_amdgcn_s_setprio(0);
      __builtin_amdgcn_s_barrier();
    }
    // ---- Phase 2: K frags i=2,3 ; stage K-b ; QK^T i=2,3 ----
    {
      const f16* kr2 = kb + (2 * 16 + cl) * 64;
      const f16* kr3 = kb + (3 * 16 + cl) * 64;
      f16x8 p2a0 = *(const f16x8*)(kr2 + ((g ^ vx) << 3));
      f16x8 p2a1 = *(const f16x8*)(kr2 + (((4 + g) ^ vx) << 3));
      f16x8 p2b0 = *(const f16x8*)(kr3 + ((g ^ vx) << 3));
      f16x8 p2b1 = *(const f16x8*)(kr3 + (((4 + g) ^ vx) << 3));
      if (st) STG_K(it + 2, nb, 1);
      __builtin_amdgcn_s_barrier();
      asm volatile("s_waitcnt lgkmcnt(0)" ::: "memory");
      __builtin_amdgcn_sched_barrier(0);
      __builtin_amdgcn_s_setprio(1);
      s[0][2] = mfma16(p2a1, bq[0][1], mfma16(p2a0, bq[0][0], z4));
      s[1][2] = mfma16(p2a1, bq[1][1], mfma16(p2a0, bq[1][0], z4));
      s[0][3] = mfma16(p2b1, bq[0][1], mfma16(p2b0, bq[0][0], z4));
      s[1][3] = mfma16(p2b1, bq[1][1], mfma16(p2b0, bq[1][0], z4));
      __builtin_amdgcn_s_setprio(0);
      __builtin_amdgcn_s_barrier();
    }
    // ---- Phase 3: softmax slice 0 + V frags ks=0 ; stage V-a ; PV ks=0 ----
    {
      PB pb0[2];
#pragma unroll
      for (int qh = 0; qh < 2; ++qh) {
        float p0 = exp2f(s[qh][0][0]), p1 = exp2f(s[qh][0][1]);
        float p2 = exp2f(s[qh][0][2]), p3 = exp2f(s[qh][0][3]);
        float p4 = exp2f(s[qh][1][0]), p5 = exp2f(s[qh][1][1]);
        float p6 = exp2f(s[qh][1][2]), p7 = exp2f(s[qh][1][3]);
        lsp[qh] += ((p0 + p1) + (p2 + p3)) + ((p4 + p5) + (p6 + p7));
        pb0[qh].hx[0] = cvt2(p0, p1);
        pb0[qh].hx[1] = cvt2(p2, p3);
        pb0[qh].hx[2] = cvt2(p4, p5);
        pb0[qh].hx[3] = cvt2(p6, p7);
      }
      f16x8 va0 = *(const f16x8*)(vb + (0 * 16 + cl) * 64 + ((g ^ vx) << 3));
      f16x8 va1 = *(const f16x8*)(vb + (1 * 16 + cl) * 64 + ((g ^ vx) << 3));
      f16x8 va2 = *(const f16x8*)(vb + (2 * 16 + cl) * 64 + ((g ^ vx) << 3));
      f16x8 va3 = *(const f16x8*)(vb + (3 * 16 + cl) * 64 + ((g ^ vx) << 3));
      if (st) STG_V(it + 2, nb, 0);
      __builtin_amdgcn_s_barrier();
      asm volatile("s_waitcnt lgkmcnt(0)" ::: "memory");
      __builtin_amdgcn_sched_barrier(0);
      __builtin_amdgcn_s_setprio(1);
      acc[0][0] = mfma16(va0, pb0[0].v, acc[0][0]);
      acc[1][0] = mfma16(va0, pb0[1].v, acc[1][0]);
      acc[0][1] = mfma16(va1, pb0[0].v, acc[0][1]);
      acc[1][1] = mfma16(va1, pb0[1].v, acc[1][1]);
      acc[0][2] = mfma16(va2, pb0[0].v, acc[0][2]);
      acc[1][2] = mfma16(va2, pb0[1].v, acc[1][2]);
      acc[0][3] = mfma16(va3, pb0[0].v, acc[0][3]);
      acc[1][3] = mfma16(va3, pb0[1].v, acc[1][3]);
      __builtin_amdgcn_s_setprio(0);
      __builtin_amdgcn_s_barrier();
    }
    // ---- Phase 4: softmax slice 1 + V frags ks=1 ; stage V-b ; PV ks=1 ----
    {
      PB pb1[2];
#pragma unroll
      for (int qh = 0; qh < 2; ++qh) {
        float p0 = exp2f(s[qh][2][0]), p1 = exp2f(s[qh][2][1]);
        float p2 = exp2f(s[qh][2][2]), p3 = exp2f(s[qh][2][3]);
        float p4 = exp2f(s[qh][3][0]), p5 = exp2f(s[qh][3][1]);
        float p6 = exp2f(s[qh][3][2]), p7 = exp2f(s[qh][3][3]);
        lsp[qh] += ((p0 + p1) + (p2 + p3)) + ((p4 + p5) + (p6 + p7));
        pb1[qh].hx[0] = cvt2(p0, p1);
        pb1[qh].hx[1] = cvt2(p2, p3);
        pb1[qh].hx[2] = cvt2(p4, p5);
        pb1[qh].hx[3] = cvt2(p6, p7);
      }
      f16x8 vc0 = *(const f16x8*)(vb + (0 * 16 + cl) * 64 + (((4 + g) ^ vx) << 3));
      f16x8 vc1 = *(const f16x8*)(vb + (1 * 16 + cl) * 64 + (((4 + g) ^ vx) << 3));
      f16x8 vc2 = *(const f16x8*)(vb + (2 * 16 + cl) * 64 + (((4 + g) ^ vx) << 3));
      f16x8 vc3 = *(const f16x8*)(vb + (3 * 16 + cl) * 64 + (((4 + g) ^ vx) << 3));
      if (st) STG_V(it + 2, nb, 1);
      __builtin_amdgcn_s_barrier();
      asm volatile("s_waitcnt lgkmcnt(0)" ::: "memory");
      __builtin_amdgcn_sched_barrier(0);
      __builtin_amdgcn_s_setprio(1);
      acc[0][0] = mfma16(vc0, pb1[0].v, acc[0][0]);
      acc[1][0] = mfma16(vc0, pb1[1].v, acc[1][0]);
      acc[0][1] = mfma16(vc1, pb1[0].v, acc[0][1]);
      acc[1][1] = mfma16(vc1, pb1[1].v, acc[1][1]);
      acc[0][2] = mfma16(vc2, pb1[0].v, acc[0][2]);
      acc[1][2] = mfma16(vc2, pb1[1].v, acc[1][2]);
      acc[0][3] = mfma16(vc3, pb1[0].v, acc[0][3]);
      acc[1][3] = mfma16(vc3, pb1[1].v, acc[1][3]);
      __builtin_amdgcn_s_setprio(0);
      // closing barrier of Ph4 = next iteration's top barrier
    }
    cur = (cur == 2) ? 0 : cur + 1;
  }
#undef STG_K
#undef STG_V

#pragma unroll
  for (int qh = 0; qh < 2; ++qh) {
    float ls = lsp[qh];
    ls += __shfl_xor(ls, 16);
    ls += __shfl_xor(ls, 32);
    float inv = 1.0f / ls;
    float* ob = out + (size_t)(b * 2048 + qb + qh * 16 + cl) * 1024 +
                h * 64 + g * 4;
#pragma unroll
    for (int d = 0; d < 4; ++d) {
      float4 o = {acc[qh][d][0] * inv, acc[qh][d][1] * inv,
                  acc[qh][d][2] * inv, acc[qh][d][3] * inv};
      *(float4*)(ob + (size_t)d * 16) = o;
    }
  }
}

extern "C" void kernel_launch(void* const* d_in, const int* in_sizes, int n_in,
                              void* d_out, int out_size, void* d_ws, size_t ws_size,
                              hipStream_t stream) {
  const float* x  = (const float*)d_in[0];
  const float* Wq = (const float*)d_in[1];
  const float* Wk = (const float*)d_in[2];
  const float* Wv = (const float*)d_in[3];
  float* out = (float*)d_out;
  char* ws = (char*)d_ws;

  f16* xh   = (f16*)(ws);                       // 8388608 B
  f16* wh   = (f16*)(ws + 8388608);             // 6291456 B
  f16* Qr   = (f16*)(ws + 14680064);            // 8388608 B
  f16* Kr   = (f16*)(ws + 23068672);            // 8388608 B
  f16* Vt   = (f16*)(ws + 31457280);            // 8388608 B
  float* cosT = (float*)(ws + 39845888);        // 262144 B
  float* sinT = (float*)(ws + 40108032);        // total ~40.4 MB

  convall<<<3840, 256, 0, stream>>>(x, Wq, Wk, Wv, xh, wh, cosT, sinT);

  dim3 g1(32, 24);
  qkv_gemm<<<g1, 256, 0, stream>>>(xh, wh, cosT, sinT, Qr, Kr, Vt);

  attn<<<512, 256, 0, stream>>>(Qr, Kr, Vt, out);
}